// Round 5
// baseline (289.977 us; speedup 1.0000x reference)
//
#include <hip/hip_runtime.h>

typedef unsigned short u16;
typedef __attribute__((ext_vector_type(8))) __bf16 bf16x8;
typedef __attribute__((ext_vector_type(4))) float f32x4;
typedef __attribute__((ext_vector_type(4))) u16 u16x4;

#define NB 4
#define NQ 2048
#define NKV 1024
#define NH 16
#define DH 64
#define DIN 1024
#define DCTX 768
#define NEGBIG -1e30f
#define QSC 0.180336881f   // 0.125 * log2(e): softmax scale folded into Q, exp -> exp2

__device__ inline u16 f2bf(float f) {
  unsigned u = __builtin_bit_cast(unsigned, f);
  u += 0x7FFFu + ((u >> 16) & 1u);
  return (u16)(u >> 16);
}

__device__ inline unsigned cvtpk(float lo, float hi) {
  unsigned r;
  asm("v_cvt_pk_bf16_f32 %0, %1, %2" : "=v"(r) : "v"(lo), "v"(hi));
  return r;
}

__device__ inline float exp2a(float x) {  // v_exp_f32 computes 2^x natively
  float r;
  asm("v_exp_f32 %0, %1" : "=v"(r) : "v"(x));
  return r;
}

// ---------------- mask dtype detection + bias build ----------------
__global__ __launch_bounds__(256) void build_bias(const void* __restrict__ mask,
                                                  float* __restrict__ biasg) {
  __shared__ int notInt, notFloat;
  if (threadIdx.x == 0) { notInt = 0; notFloat = 0; }
  __syncthreads();
  const unsigned* mw = (const unsigned*)mask;
  int bad_i = 0, bad_f = 0;
#pragma unroll
  for (int e = 0; e < 4; e++) {
    unsigned v = mw[threadIdx.x * 4 + e];
    if (v > 1u) bad_i = 1;
    if (v != 0u && v != 0x3f800000u) bad_f = 1;
  }
  if (bad_i) atomicOr(&notInt, 1);
  if (bad_f) atomicOr(&notFloat, 1);
  __syncthreads();
  const int isInt = !notInt, isFloat = !notFloat;
  for (int i = threadIdx.x; i < NB * NKV; i += 256) {
    bool on;
    if (isInt)        on = ((const int*)mask)[i] != 0;
    else if (isFloat) on = ((const float*)mask)[i] != 0.f;
    else              on = ((const unsigned char*)mask)[i] != 0;
    biasg[i] = on ? 0.f : NEGBIG;
  }
}

// ---------------- fp32 -> bf16 elementwise ----------------
__global__ __launch_bounds__(256) void cvt_bf16(const float* __restrict__ in,
                                                u16* __restrict__ out, int n) {
  int i = (blockIdx.x * 256 + threadIdx.x) * 4;
  if (i >= n) return;
  float4 v = *(const float4*)(in + i);
  u16x4 o = { f2bf(v.x), f2bf(v.y), f2bf(v.z), f2bf(v.w) };
  *(u16x4*)(out + i) = o;
}

// ---------------- W[K][N] fp32 -> Wt[N][K] bf16 ----------------
__global__ __launch_bounds__(256) void transpose_cvt(const float* __restrict__ W,
                                                     u16* __restrict__ Wt, int K, int N) {
  __shared__ float tile[32][33];
  int n0 = blockIdx.x * 32, k0 = blockIdx.y * 32;
  int tx = threadIdx.x & 31, ty = threadIdx.x >> 5;
#pragma unroll
  for (int i = 0; i < 32; i += 8)
    tile[ty + i][tx] = W[(size_t)(k0 + ty + i) * N + n0 + tx];
  __syncthreads();
#pragma unroll
  for (int i = 0; i < 32; i += 8)
    Wt[(size_t)(n0 + ty + i) * K + k0 + tx] = f2bf(tile[tx][ty + i]);
}

// ---------------- V^T: kvb V-half [4096][2048 cols 1024..2047] -> vtg [(b,h),d,j] ----------------
__global__ __launch_bounds__(256) void vtrans(const u16* __restrict__ kvb, u16* __restrict__ vtg) {
  __shared__ __align__(16) u16 tile[64][72];
  const int t = threadIdx.x;
  const int jt = blockIdx.x, bh = blockIdx.y;
  const int b = bh >> 4, h = bh & 15;
  const int j0 = jt * 64;
  const int jl = t >> 2, c2 = t & 3;
  const u16* src = kvb + (size_t)(b * 1024 + j0 + jl) * 2048 + 1024 + h * 64 + c2 * 16;
  *(int4*)&tile[jl][c2 * 16]     = *(const int4*)(src);
  *(int4*)&tile[jl][c2 * 16 + 8] = *(const int4*)(src + 8);
  __syncthreads();
  const int dl = t >> 2;
  union { u16 e[16]; int4 q[2]; } pk;
#pragma unroll
  for (int e = 0; e < 16; e++) pk.e[e] = tile[c2 * 16 + e][dl];
  u16* dst = vtg + (size_t)(bh * 64 + dl) * 1024 + j0 + c2 * 16;
  *(int4*)dst       = pk.q[0];
  *(int4*)(dst + 8) = pk.q[1];
}

// ---------------- bf16 GEMM: C = A * Bt^T, 3-buf 2-ahead counted-vmcnt pipeline ----------------
// mode: 0 = f32 + bias, 1 = bf16, 2 = bf16 * QSC. Two problem descs; blocks < split run desc0.
__global__ __launch_bounds__(256) void gemm_pipe(
    const u16* __restrict__ A0, const u16* __restrict__ B0, void* __restrict__ C0,
    const float* __restrict__ bias0, int N0, int K0, int mode0, int gx0,
    const u16* __restrict__ A1, const u16* __restrict__ B1, void* __restrict__ C1,
    const float* __restrict__ bias1, int N1, int K1, int mode1, int gx1, int split) {
  __shared__ __align__(16) u16 As[3 * 4096];
  __shared__ __align__(16) u16 Bs[3 * 4096];
  const u16 *A, *Bt; void* Cout; const float* bias;
  int N, K, mode, bx, by;
  {
    int bi = blockIdx.x;
    if (bi < split) { A = A0; Bt = B0; Cout = C0; bias = bias0; N = N0; K = K0; mode = mode0; bx = bi % gx0; by = bi / gx0; }
    else { bi -= split; A = A1; Bt = B1; Cout = C1; bias = bias1; N = N1; K = K1; mode = mode1; bx = bi % gx1; by = bi / gx1; }
  }
  const int t = threadIdx.x, w = t >> 6, l = t & 63, g = l >> 4, m16 = l & 15;
  const int brow = by * 128, bcol = bx * 128;
  const int wr = w >> 1, wc = w & 1;
  const int r_a = t >> 2;
  const int kb  = (t & 3) * 8;
  const int nk = K >> 5;
  f32x4 acc[4][4] = {};

#define G_STAGE(ks, bsel)                                                              \
  {                                                                                    \
    int k0_ = (ks) << 5;                                                               \
    _Pragma("unroll")                                                                  \
    for (int i = 0; i < 2; i++) {                                                      \
      const u16* ga = A + (size_t)(brow + i * 64 + r_a) * K + k0_ + kb;                \
      __builtin_amdgcn_global_load_lds(                                                \
          (const __attribute__((address_space(1))) void*)ga,                           \
          (__attribute__((address_space(3))) void*)((char*)As + (bsel) * 8192 + i * 4096 + w * 1024), \
          16, 0, 0);                                                                   \
      const u16* gb = Bt + (size_t)(bcol + i * 64 + r_a) * K + k0_ + kb;               \
      __builtin_amdgcn_global_load_lds(                                                \
          (const __attribute__((address_space(1))) void*)gb,                           \
          (__attribute__((address_space(3))) void*)((char*)Bs + (bsel) * 8192 + i * 4096 + w * 1024), \
          16, 0, 0);                                                                   \
    }                                                                                  \
  }

  G_STAGE(0, 0);
  G_STAGE(1, 1);
  int cur = 0, stg = 2;
  for (int ks = 0; ks < nk; ++ks) {
    if (ks + 1 < nk) asm volatile("s_waitcnt vmcnt(4)" ::: "memory");
    else             asm volatile("s_waitcnt vmcnt(0)" ::: "memory");
    asm volatile("s_barrier" ::: "memory");
    bf16x8 af[4], bfr[4];
#pragma unroll
    for (int m = 0; m < 4; m++)
      af[m] = *(const bf16x8*)(&As[cur * 4096 + (wr * 64 + m * 16 + m16) * 32 + g * 8]);
#pragma unroll
    for (int n = 0; n < 4; n++)
      bfr[n] = *(const bf16x8*)(&Bs[cur * 4096 + (wc * 64 + n * 16 + m16) * 32 + g * 8]);
    if (ks + 2 < nk) G_STAGE(ks + 2, stg);
#pragma unroll
    for (int m = 0; m < 4; m++)
#pragma unroll
      for (int n = 0; n < 4; n++)
        acc[m][n] = __builtin_amdgcn_mfma_f32_16x16x32_bf16(af[m], bfr[n], acc[m][n], 0, 0, 0);
    cur = (cur == 2) ? 0 : cur + 1;
    stg = (stg == 2) ? 0 : stg + 1;
  }
#undef G_STAGE

#pragma unroll
  for (int m = 0; m < 4; m++) {
    int grow = brow + wr * 64 + m * 16 + g * 4;
#pragma unroll
    for (int n = 0; n < 4; n++) {
      int gcol = bcol + wc * 64 + n * 16 + m16;
#pragma unroll
      for (int r = 0; r < 4; r++) {
        size_t off = (size_t)(grow + r) * N + gcol;
        if (mode == 0)      ((float*)Cout)[off] = acc[m][n][r] + bias[gcol];
        else if (mode == 1) ((u16*)Cout)[off] = f2bf(acc[m][n][r]);
        else                ((u16*)Cout)[off] = f2bf(acc[m][n][r] * QSC);
      }
    }
  }
}

// ---------------- flash attention ----------------
// swapped QK^T, fixed-max softmax (Q pre-scaled, p = 2^(s+bias)); K and V^T both staged
// via global_load_lds with pre-swizzled source; dbuf, stage issued at tile top.
// grid (32 qtiles, 16 heads, 4 batch), 256 thr = 4 waves, QBLK=64 (16 rows/wave), KVBLK=64
__global__ __launch_bounds__(256) void attn(const u16* __restrict__ Q, const u16* __restrict__ Kb,
                                            const u16* __restrict__ Vt_g,
                                            const float* __restrict__ biasg,
                                            u16* __restrict__ O) {
  const int qt = blockIdx.x, h = blockIdx.y, b = blockIdx.z;
  const int t = threadIdx.x, w = t >> 6, l = t & 63, g = l >> 4, m16 = l & 15;
  const int bh = b * NH + h;

  __shared__ __align__(16) u16 Kl[2][4096];       // [j][d-chunks], chunk pos p holds data chunk p^(j&7)
  __shared__ __align__(16) u16 Vt[2][4096];       // [d][j-chunks], chunk pos p holds data chunk p^(d&7)
  __shared__ __align__(16) unsigned Pl[4][16 * 36];
  __shared__ float biasl[NKV];

  for (int i = t; i < NKV; i += 256) biasl[i] = biasg[(size_t)b * NKV + i];

  const int qrow = qt * 64 + w * 16 + m16;
  const u16* qp = Q + (size_t)(b * NQ + qrow) * DIN + h * DH;
  bf16x8 qA0 = *(const bf16x8*)(qp + g * 8);
  bf16x8 qA1 = *(const bf16x8*)(qp + 32 + g * 8);

  f32x4 oA[4] = {};
  float lA = 0.f;

#define STAGE_K(j0, bsel)                                                     \
  {                                                                           \
    _Pragma("unroll")                                                         \
    for (int n = 0; n < 2; n++) {                                             \
      int j_ = n * 32 + (t >> 3);                                             \
      int c_ = (t & 7) ^ (j_ & 7);                                            \
      const u16* gk = Kb + (size_t)(b * NKV + (j0) + j_) * 2048 + h * DH + c_ * 8; \
      __builtin_amdgcn_global_load_lds(                                       \
          (const __attribute__((address_space(1))) void*)gk,                  \
          (__attribute__((address_space(3))) void*)((char*)Kl + (bsel) * 8192 + n * 4096 + t * 16), \
          16, 0, 0);                                                          \
    }                                                                         \
  }
#define STAGE_V(j0, bsel)                                                     \
  {                                                                           \
    _Pragma("unroll")                                                         \
    for (int n = 0; n < 2; n++) {                                             \
      int d_ = n * 32 + (t >> 3);                                             \
      int c_ = (t & 7) ^ (d_ & 7);                                            \
      const u16* gv = Vt_g + (size_t)(bh * 64 + d_) * 1024 + (j0) + c_ * 8;   \
      __builtin_amdgcn_global_load_lds(                                       \
          (const __attribute__((address_space(1))) void*)gv,                  \
          (__attribute__((address_space(3))) void*)((char*)Vt + (bsel) * 8192 + n * 4096 + t * 16), \
          16, 0, 0);                                                          \
    }                                                                         \
  }

  STAGE_K(0, 0);
  STAGE_V(0, 0);
  asm volatile("s_waitcnt vmcnt(0) lgkmcnt(0)" ::: "memory");
  asm volatile("s_barrier" ::: "memory");

  for (int it = 0; it < 16; ++it) {
    const int cur = it & 1, nxt = cur ^ 1;
    const int j0 = it * 64;
    if (it + 1 < 16) {
      STAGE_K(j0 + 64, nxt);
      STAGE_V(j0 + 64, nxt);
    }

    // ---- QK^T (swapped): lane holds S^T[j][i], i=m16 ----
    f32x4 sA[4];
#pragma unroll
    for (int jt = 0; jt < 4; jt++) {
      int jr = jt * 16 + m16;
      const u16* krow = &Kl[cur][jr * 64];
      bf16x8 kf0 = *(const bf16x8*)(krow + ((g ^ (jr & 7)) * 8));
      bf16x8 kf1 = *(const bf16x8*)(krow + (((4 + g) ^ (jr & 7)) * 8));
      f32x4 z = {};
      f32x4 t0 = __builtin_amdgcn_mfma_f32_16x16x32_bf16(kf0, qA0, z, 0, 0, 0);
      sA[jt]   = __builtin_amdgcn_mfma_f32_16x16x32_bf16(kf1, qA1, t0, 0, 0, 0);
    }
    float4 b4[4];
#pragma unroll
    for (int jt = 0; jt < 4; jt++) b4[jt] = *(const float4*)&biasl[j0 + jt * 16 + g * 4];

    unsigned* plw = &Pl[w][0];
#pragma unroll
    for (int jt = 0; jt < 4; jt++) {
      float p0 = exp2a(sA[jt][0] + b4[jt].x);
      float p1 = exp2a(sA[jt][1] + b4[jt].y);
      float p2 = exp2a(sA[jt][2] + b4[jt].z);
      float p3 = exp2a(sA[jt][3] + b4[jt].w);
      lA += (p0 + p1) + (p2 + p3);
      uint2 u; u.x = cvtpk(p0, p1); u.y = cvtpk(p2, p3);
      *(uint2*)&plw[m16 * 36 + jt * 8 + 2 * g] = u;
    }
    asm volatile("" ::: "memory");
    bf16x8 pf0 = *(const bf16x8*)&plw[m16 * 36 + 4 * g];
    bf16x8 pf1 = *(const bf16x8*)&plw[m16 * 36 + 16 + 4 * g];
#pragma unroll
    for (int dt = 0; dt < 4; dt++) {
      int d = dt * 16 + m16;
      const u16* vrow = &Vt[cur][d * 64];
      bf16x8 vf0 = *(const bf16x8*)(vrow + ((g ^ (d & 7)) * 8));
      bf16x8 vf1 = *(const bf16x8*)(vrow + (((4 + g) ^ (d & 7)) * 8));
      oA[dt] = __builtin_amdgcn_mfma_f32_16x16x32_bf16(pf0, vf0, oA[dt], 0, 0, 0);
      oA[dt] = __builtin_amdgcn_mfma_f32_16x16x32_bf16(pf1, vf1, oA[dt], 0, 0, 0);
    }
    asm volatile("s_waitcnt vmcnt(0)" ::: "memory");
    asm volatile("s_barrier" ::: "memory");
  }
#undef STAGE_K
#undef STAGE_V

  lA += __shfl_xor(lA, 16); lA += __shfl_xor(lA, 32);
  float invA[4];
#pragma unroll
  for (int r = 0; r < 4; r++) invA[r] = 1.f / __shfl(lA, g * 4 + r);
  u16* op = O + (size_t)(b * NQ + qt * 64 + w * 16) * DIN + h * DH;
#pragma unroll
  for (int dt = 0; dt < 4; dt++)
#pragma unroll
    for (int r = 0; r < 4; r++)
      op[(size_t)(g * 4 + r) * DIN + dt * 16 + m16] = f2bf(oA[dt][r] * invA[r]);
}

// ---------------- launcher ----------------
extern "C" void kernel_launch(void* const* d_in, const int* in_sizes, int n_in,
                              void* d_out, int out_size, void* d_ws, size_t ws_size,
                              hipStream_t stream) {
  const float* x   = (const float*)d_in[0];
  const float* ctx = (const float*)d_in[1];
  const void*  mask = (const void*)d_in[2];
  const float* Wq  = (const float*)d_in[3];
  const float* Wk  = (const float*)d_in[4];
  const float* Wv  = (const float*)d_in[5];
  const float* Wo  = (const float*)d_in[6];
  const float* bo  = (const float*)d_in[7];
  float* out = (float*)d_out;

  char* ws = (char*)d_ws;
  u16* xb   = (u16*)(ws);                  // [8192][1024] bf16 (reused as ab)
  u16* cb   = (u16*)(ws + 16777216);       // [4096][768]
  u16* wqt  = (u16*)(ws + 23068672);       // [1024][1024]
  u16* wkv  = (u16*)(ws + 25165824);       // [2048][768]  (Wk^T | Wv^T)
  u16* wot  = (u16*)(ws + 28311552);       // [1024][1024]
  u16* qb   = (u16*)(ws + 30408704);       // [8192][1024]
  u16* kvb  = (u16*)(ws + 47185920);       // [4096][2048] (K | V interleaved)
  u16* vtg  = (u16*)(ws + 16777216);       // [(b,h)*64+d][1024] — overlaps cb/wqt (dead by vtrans)
  float* biasg = (float*)(ws + 63963136);  // [4][1024]
  u16* ab   = xb;

  build_bias<<<1, 256, 0, stream>>>(mask, biasg);
  cvt_bf16<<<8192, 256, 0, stream>>>(x, xb, 8388608);
  cvt_bf16<<<3072, 256, 0, stream>>>(ctx, cb, 3145728);
  transpose_cvt<<<dim3(32, 32), 256, 0, stream>>>(Wq, wqt, 1024, 1024);
  transpose_cvt<<<dim3(32, 24), 256, 0, stream>>>(Wk, wkv, 768, 1024);
  transpose_cvt<<<dim3(32, 24), 256, 0, stream>>>(Wv, wkv + 1024 * 768, 768, 1024);
  transpose_cvt<<<dim3(32, 32), 256, 0, stream>>>(Wo, wot, 1024, 1024);

  // fused: blocks [0,512) = Q proj (mode 2), [512,1024) = K|V proj (mode 1)
  gemm_pipe<<<1024, 256, 0, stream>>>(
      xb, wqt, qb, nullptr, 1024, 1024, 2, 8,
      cb, wkv, kvb, nullptr, 2048, 768, 1, 16, 512);

  vtrans<<<dim3(16, 64), 256, 0, stream>>>(kvb, vtg);

  attn<<<dim3(32, 16, 4), 256, 0, stream>>>(qb, kvb, vtg, biasg, ab);

  gemm_pipe<<<512, 256, 0, stream>>>(
      ab, wot, out, bo, 1024, 1024, 0, 8,
      ab, wot, out, bo, 1024, 1024, 0, 8, 512);
}